// Round 5
// baseline (450.520 us; speedup 1.0000x reference)
//
#include <hip/hip_runtime.h>
#include <stdint.h>

#define B_   256
#define M_   80
#define T_   1000
#define H_   128
#define G3   384
#define TILE 32
#define NT_  32          // ceil(1000/32); last tile has 8 steps
#define XPAD 104         // x-tile row pad (mel 80 -> 104)
#define GPAD 388         // gxt row pad: 776 B -> 4*rowstride = 8 banks offset/kq row

typedef _Float16 half8 __attribute__((ext_vector_type(8)));
typedef float    f32x4 __attribute__((ext_vector_type(4)));

#define SCL_RZ (-1.44269504f)   // -log2(e): sigmoid(v) = rcp(1+exp2(SCL_RZ*v))
#define SCL_N  ( 2.88539008f)   // 2*log2(e): tanh(v) = 1-2*rcp(1+exp2(SCL_N*v))
#define MFMA(A, Bf, C) __builtin_amdgcn_mfma_f32_16x16x32_f16((A), (Bf), (C), 0, 0, 0)

// One block per batch element (grid 256 = CU count), 512 thr = 8 waves (2/SIMD).
// Structure/schedule = round-0 champion (390us) EXACTLY; the only change is
// scale-folding: all weights/biases feeding the exp2-based gates are pre-scaled
// at frag-load time (wr/wz x -log2e; wn,bN x 2log2e; wih/biasA per-gate), so
// gxt stores pre-scaled projections and the per-step tail is exp2-direct with
// zero multiplies on the serial r->tanh chain. Falsified by measurement in
// R1-R4: LDS throughput, MFMA chain depth, phase-A interleave, VALU volume.
__global__ __launch_bounds__(512, 2) void gru_tile(
    const float* __restrict__ x,      // (B, M, T)
    const float* __restrict__ W_ih,   // (3H, M)
    const float* __restrict__ W_hh,   // (3H, H)
    const float* __restrict__ b_ih,   // (3H,)
    const float* __restrict__ b_hh,   // (3H,)
    float* __restrict__ out)          // (B, H)
{
    const int b   = blockIdx.x;
    const int tid = threadIdx.x;
    const int l   = tid & 63;
    const int w   = tid >> 6;      // wave 0..7
    const int jn  = l & 15;        // MFMA n / m row within tile
    const int kq  = l >> 4;        // quad: k-base 8*kq
    const int hid = 16 * w + jn;   // hidden unit owned (recurrence N)

    __shared__ __align__(16) _Float16 gxt[TILE][GPAD];      // gate inputs (pre-scaled)
    __shared__ __align__(16) _Float16 xt16[2][TILE][XPAD];  // x tiles [t][mel], dbuf
    __shared__ __align__(16) _Float16 h16[2][H_];           // h state, dbuf

    // ---- W_hh B-frags, pre-scaled: wr/wz x SCL_RZ, wn x SCL_N ----
    half8 wr[4], wz[4], wn[4];
#pragma unroll
    for (int f = 0; f < 4; ++f)
#pragma unroll
        for (int j = 0; j < 8; ++j) {
            const int k = 32 * f + 8 * kq + j;
            wr[f][j] = (_Float16)(SCL_RZ * W_hh[(hid)          * H_ + k]);
            wz[f][j] = (_Float16)(SCL_RZ * W_hh[(H_ + hid)     * H_ + k]);
            wn[f][j] = (_Float16)(SCL_N  * W_hh[(2 * H_ + hid) * H_ + k]);
        }
#pragma unroll
    for (int f = 0; f < 4; ++f) {
        asm volatile("" : "+v"(wr[f]));
        asm volatile("" : "+v"(wz[f]));
        asm volatile("" : "+v"(wn[f]));
    }

    // ---- W_ih B-frags (phase A), pre-scaled per gate so gxt is pre-scaled ----
    half8 wih[3][3];
    float biasA[3];
#pragma unroll
    for (int i = 0; i < 3; ++i) {
        const int g = 16 * (3 * w + i) + jn;
        const float scl = (g < 2 * H_) ? SCL_RZ : SCL_N;
        biasA[i] = scl * (b_ih[g] + (g < 2 * H_ ? b_hh[g] : 0.0f));
        const float* wp = W_ih + g * M_;
#pragma unroll
        for (int f = 0; f < 3; ++f)
#pragma unroll
            for (int j = 0; j < 8; ++j) {
                const int k = 32 * f + 8 * kq + j;
                wih[i][f][j] = (k < M_) ? (_Float16)(scl * wp[k]) : (_Float16)0.0f;
            }
    }
#pragma unroll
    for (int i = 0; i < 3; ++i) {
        asm volatile("" : "+v"(wih[i][0]));
        asm volatile("" : "+v"(wih[i][1]));
        asm volatile("" : "+v"(wih[i][2]));
    }
    asm volatile("" : "+v"(biasA[0]), "+v"(biasA[1]), "+v"(biasA[2]));

    const float bNs = SCL_N * b_hh[2 * H_ + hid];   // pre-scaled n-gate hidden bias
    const f32x4 zero4 = { 0.f, 0.f, 0.f, 0.f };
    const f32x4 bN4   = { bNs, bNs, bNs, bNs };     // N-chain C-init (replaces tail add)
    const float* xb = x + (size_t)b * M_ * T_;

    // ---- init: zero x-tile pads + h0, then stage x tile 0 ----
    for (int i = tid; i < 2 * TILE * XPAD; i += 512) ((short*)xt16)[i] = 0;
    if (tid < H_) h16[0][tid] = (_Float16)0.0f;
    __syncthreads();
    {
        const int tq = tid & 7, m0 = tid >> 3;     // 64 mels x 8 quads
        float4 v0 = *(const float4*)&xb[(size_t)m0 * T_ + 4 * tq];
#pragma unroll
        for (int e = 0; e < 4; ++e) xt16[0][4 * tq + e][m0] = (_Float16)v0[e];
        if (tid < 128) {
            float4 v1 = *(const float4*)&xb[(size_t)(64 + m0) * T_ + 4 * tq];
#pragma unroll
            for (int e = 0; e < 4; ++e) xt16[0][4 * tq + e][64 + m0] = (_Float16)v1[e];
        }
    }
    __syncthreads();

    float h_r = 0.0f;

    for (int tb = 0; tb < NT_; ++tb) {
        // ================= phase A =================
        // prefetch next x tile (t1 multiple of 4; T_ multiple of 4 -> no straddle)
        const int t1 = TILE * (tb + 1);
        const int tq = tid & 7, m0 = tid >> 3;
        float4 xv0, xv1;
        const bool doPref = (t1 < T_);
        if (doPref) {
            const int tc0 = t1 + 4 * tq;
            const int tc  = (tc0 <= T_ - 4) ? tc0 : (T_ - 4);  // clamped slots unused
            xv0 = *(const float4*)&xb[(size_t)m0 * T_ + tc];
            if (tid < 128) xv1 = *(const float4*)&xb[(size_t)(64 + m0) * T_ + tc];
        }
        // gxt = scl * (x_tile . W_ih^T + bias) (dense-M MFMA; M = t)
        const int cbuf = tb & 1, nbuf = cbuf ^ 1;
#pragma unroll
        for (int mt = 0; mt < 2; ++mt) {
            half8 af[3];
#pragma unroll
            for (int f = 0; f < 3; ++f)
                af[f] = *(const half8*)&xt16[cbuf][16 * mt + jn][32 * f + 8 * kq];
#pragma unroll
            for (int i = 0; i < 3; ++i) {
                f32x4 acc = { biasA[i], biasA[i], biasA[i], biasA[i] };
                acc = MFMA(af[0], wih[i][0], acc);
                acc = MFMA(af[1], wih[i][1], acc);
                acc = MFMA(af[2], wih[i][2], acc);
                const int g    = 16 * (3 * w + i) + jn;
                const int trow = 16 * mt + 4 * kq;
#pragma unroll
                for (int r2 = 0; r2 < 4; ++r2)
                    gxt[trow + r2][g] = (_Float16)acc[r2];
            }
        }
        // publish prefetched x tile
        if (doPref) {
#pragma unroll
            for (int e = 0; e < 4; ++e) xt16[nbuf][4 * tq + e][m0] = (_Float16)xv0[e];
            if (tid < 128) {
#pragma unroll
                for (int e = 0; e < 4; ++e) xt16[nbuf][4 * tq + e][64 + m0] = (_Float16)xv1[e];
            }
        }
        __syncthreads();     // gxt + next x tile ready

        // ================= phase B: recurrence steps =================
        const int rem    = T_ - TILE * tb;
        const int nsteps = (rem < TILE) ? rem : TILE;   // 32 or 8 (both even)
        for (int tt = 0; tt < nsteps; tt += 2) {
            // ---- even step: reads h16[0], writes h16[1] ----
            {
                const int ko = 8 * kq;
                const half8 a0 = *(const half8*)&h16[0][ko];
                const half8 a1 = *(const half8*)&h16[0][32 + ko];
                const half8 a2 = *(const half8*)&h16[0][64 + ko];
                const half8 a3 = *(const half8*)&h16[0][96 + ko];
                const float gr = (float)gxt[tt][hid];
                const float gz = (float)gxt[tt][H_ + hid];
                const float gn = (float)gxt[tt][2 * H_ + hid];
                f32x4 aR = MFMA(a0, wr[0], zero4);
                f32x4 aZ = MFMA(a0, wz[0], zero4);
                f32x4 aN = MFMA(a0, wn[0], bN4);
                aR = MFMA(a1, wr[1], aR); aZ = MFMA(a1, wz[1], aZ); aN = MFMA(a1, wn[1], aN);
                aR = MFMA(a2, wr[2], aR); aZ = MFMA(a2, wz[2], aZ); aN = MFMA(a2, wn[2], aN);
                aR = MFMA(a3, wr[3], aR); aZ = MFMA(a3, wz[3], aZ); aN = MFMA(a3, wn[3], aN);
                const float r  = __builtin_amdgcn_rcpf(
                    1.0f + __builtin_amdgcn_exp2f(aR[0] + gr));
                const float z  = __builtin_amdgcn_rcpf(
                    1.0f + __builtin_amdgcn_exp2f(aZ[0] + gz));
                const float q  = __builtin_amdgcn_rcpf(
                    1.0f + __builtin_amdgcn_exp2f(fmaf(r, aN[0], gn)));
                const float nv = fmaf(-2.0f, q, 1.0f);
                h_r = fmaf(z, h_r - nv, nv);
                if (l < 16) h16[1][hid] = (_Float16)h_r;
            }
            __syncthreads();
            // ---- odd step: reads h16[1], writes h16[0] ----
            {
                const int ko = 8 * kq;
                const half8 a0 = *(const half8*)&h16[1][ko];
                const half8 a1 = *(const half8*)&h16[1][32 + ko];
                const half8 a2 = *(const half8*)&h16[1][64 + ko];
                const half8 a3 = *(const half8*)&h16[1][96 + ko];
                const float gr = (float)gxt[tt + 1][hid];
                const float gz = (float)gxt[tt + 1][H_ + hid];
                const float gn = (float)gxt[tt + 1][2 * H_ + hid];
                f32x4 aR = MFMA(a0, wr[0], zero4);
                f32x4 aZ = MFMA(a0, wz[0], zero4);
                f32x4 aN = MFMA(a0, wn[0], bN4);
                aR = MFMA(a1, wr[1], aR); aZ = MFMA(a1, wz[1], aZ); aN = MFMA(a1, wn[1], aN);
                aR = MFMA(a2, wr[2], aR); aZ = MFMA(a2, wz[2], aZ); aN = MFMA(a2, wn[2], aN);
                aR = MFMA(a3, wr[3], aR); aZ = MFMA(a3, wz[3], aZ); aN = MFMA(a3, wn[3], aN);
                const float r  = __builtin_amdgcn_rcpf(
                    1.0f + __builtin_amdgcn_exp2f(aR[0] + gr));
                const float z  = __builtin_amdgcn_rcpf(
                    1.0f + __builtin_amdgcn_exp2f(aZ[0] + gz));
                const float q  = __builtin_amdgcn_rcpf(
                    1.0f + __builtin_amdgcn_exp2f(fmaf(r, aN[0], gn)));
                const float nv = fmaf(-2.0f, q, 1.0f);
                h_r = fmaf(z, h_r - nv, nv);
                if (l < 16) h16[0][hid] = (_Float16)h_r;
            }
            __syncthreads();
        }
    }

    if (l < 16) out[(size_t)b * H_ + hid] = h_r;
}

extern "C" void kernel_launch(void* const* d_in, const int* in_sizes, int n_in,
                              void* d_out, int out_size, void* d_ws, size_t ws_size,
                              hipStream_t stream) {
    const float* x    = (const float*)d_in[0];
    const float* W_ih = (const float*)d_in[1];
    const float* W_hh = (const float*)d_in[2];
    const float* b_ih = (const float*)d_in[3];
    const float* b_hh = (const float*)d_in[4];
    float* out = (float*)d_out;

    gru_tile<<<dim3(B_), dim3(512), 0, stream>>>(x, W_ih, W_hh, b_ih, b_hh, out);
}